// Round 1
// 602.280 us; speedup vs baseline: 1.0944x; 1.0944x over previous
//
#include <hip/hip_runtime.h>
#include <math.h>

// ---------------- problem constants ----------------
#define BQ    1024
#define NB    131072
#define DS    64
#define DF    256
#define KSEL  16

// ---------------- score kernel tiling ----------------
#define QT    128        // queries per block (4 waves x 32)
#define BC    64         // blobs per chunk
#define PCH   64         // chunk stripes (grid.x)
#define NCHUNK (NB / BC)             // 2048
#define CHUNKS_PER_BLK (NCHUNK/PCH)  // 32
#define CPQ   (PCH * KSEL)           // 1024 candidates per query
#define SLD   68                     // Stile leading dim (floats, 272B rows, 16B-aligned)

// Bprep layout per chunk: [split(2)][ntile(4)][kstep(4)][lane(64)][16B] = 32 KB
#define CH_BYTES   32768
#define SPLIT_OFF  16384

typedef __bf16 bf16x8 __attribute__((ext_vector_type(8)));
typedef float  f32x4  __attribute__((ext_vector_type(4)));
typedef unsigned long long u64;

#define ENC_NEGINF 0x007FFFFFu   // map_f32(-inf)

__device__ __forceinline__ unsigned map_f32(float s) {
    unsigned u = __float_as_uint(s);
    return (u & 0x80000000u) ? ~u : (u | 0x80000000u);
}

__device__ __forceinline__ float unmap_f32(unsigned e) {
    return __uint_as_float((e & 0x80000000u) ? (e & 0x7FFFFFFFu) : ~e);
}

__device__ __forceinline__ void async_cp16(const void* g, void* l) {
    __builtin_amdgcn_global_load_lds(
        (const __attribute__((address_space(1))) unsigned int*)g,
        (__attribute__((address_space(3))) unsigned int*)l, 16, 0, 0);
}

// ---------------- fused preprocess: fragments + m2 + log-alpha ----------------
// thread = (blob, dd): 8 consecutive d of one blob; computes iv once,
// emits hi/lo bf16 frags for BOTH rows (iv, mu*iv), partial m2 via shuffle.
__global__ __launch_bounds__(256)
void prep_kernel(const float* __restrict__ mu,
                 const float* __restrict__ log_var,
                 const float* __restrict__ raw_alpha,
                 char* __restrict__ bprep,
                 float* __restrict__ m2la,
                 unsigned* __restrict__ gcut)
{
    int gid  = blockIdx.x * 256 + threadIdx.x;   // NB*8 = 2^20 threads
    if (gid < BQ) gcut[gid] = ENC_NEGINF;        // re-init global cutoffs each launch
    int blob = gid >> 3;
    int dd   = gid & 7;

    const float* mrow = mu      + (size_t)blob * DS + dd * 8;
    const float* vrow = log_var + (size_t)blob * DS + dd * 8;
    float4 ma = ((const float4*)mrow)[0], mb = ((const float4*)mrow)[1];
    float4 va = ((const float4*)vrow)[0], vb = ((const float4*)vrow)[1];
    float m[8] = {ma.x, ma.y, ma.z, ma.w, mb.x, mb.y, mb.z, mb.w};
    float lv[8] = {va.x, va.y, va.z, va.w, vb.x, vb.y, vb.z, vb.w};

    bf16x8 hiv, liv, hmv, lmv;
    float p = 0.0f;
    #pragma unroll
    for (int j = 0; j < 8; ++j) {
        float iv = __expf(-lv[j]);
        float mv = m[j] * iv;
        p += m[j] * mv;
        __bf16 h1 = (__bf16)iv;  hiv[j] = h1; liv[j] = (__bf16)(iv - (float)h1);
        __bf16 h2 = (__bf16)mv;  hmv[j] = h2; lmv[j] = (__bf16)(mv - (float)h2);
    }
    p += __shfl_xor(p, 1);
    p += __shfl_xor(p, 2);
    p += __shfl_xor(p, 4);

    int c  = blob >> 6;
    int nt = (blob >> 4) & 3;
    int bl = blob & 15;
    int lane  = (dd & 3) * 16 + bl;
    int ks_iv = dd >> 2;            // k = dd*8      (iv rows: k in [0,64))
    int ks_mv = 2 + (dd >> 2);      // k = 64+dd*8   (mu*iv rows)
    size_t b_iv = (size_t)c * CH_BYTES + nt * 4096 + ks_iv * 1024 + lane * 16;
    size_t b_mv = (size_t)c * CH_BYTES + nt * 4096 + ks_mv * 1024 + lane * 16;
    *(bf16x8*)(bprep + b_iv)             = hiv;
    *(bf16x8*)(bprep + b_iv + SPLIT_OFF) = liv;
    *(bf16x8*)(bprep + b_mv)             = hmv;
    *(bf16x8*)(bprep + b_mv + SPLIT_OFF) = lmv;

    if (dd == 0) {
        m2la[blob * 2]     = p;
        m2la[blob * 2 + 1] = -log1pf(__expf(-raw_alpha[blob]));  // log sigmoid
    }
}

// ---------------- register top-16 insertion (tree argmin, unsorted) ----------------
__device__ __forceinline__ void ins16(float (&ts)[16], int (&ti)[16],
                                      float& mymin, float s, int idx)
{
    float v0[8]; int j0[8];
    #pragma unroll
    for (int i = 0; i < 8; ++i) {
        bool b = ts[2*i+1] < ts[2*i];
        v0[i] = b ? ts[2*i+1] : ts[2*i];
        j0[i] = (i << 1) | (b ? 1 : 0);
    }
    float v1[4]; int j1[4];
    #pragma unroll
    for (int i = 0; i < 4; ++i) {
        bool b = v0[2*i+1] < v0[2*i];
        v1[i] = b ? v0[2*i+1] : v0[2*i];
        j1[i] = b ? j0[2*i+1] : j0[2*i];
    }
    float v2[2]; int j2[2];
    #pragma unroll
    for (int i = 0; i < 2; ++i) {
        bool b = v1[2*i+1] < v1[2*i];
        v2[i] = b ? v1[2*i+1] : v1[2*i];
        j2[i] = b ? j1[2*i+1] : j1[2*i];
    }
    int am = (v2[1] < v2[0]) ? j2[1] : j2[0];
    #pragma unroll
    for (int i = 0; i < 16; ++i) {
        bool b = (i == am);
        ts[i] = b ? s : ts[i];
        ti[i] = b ? idx : ti[i];
    }
    float n0[8];
    #pragma unroll
    for (int i = 0; i < 8; ++i) n0[i] = fminf(ts[2*i], ts[2*i+1]);
    float n1[4];
    #pragma unroll
    for (int i = 0; i < 4; ++i) n1[i] = fminf(n0[2*i], n0[2*i+1]);
    mymin = fminf(fminf(n1[0], n1[1]), fminf(n1[2], n1[3]));
}

// ---------------- score + top-k kernel ----------------
__global__ __launch_bounds__(256, 2)
void score_topk_kernel(const float* __restrict__ query,
                       const char* __restrict__ bprep,
                       const float* __restrict__ m2la,
                       const float* __restrict__ log_tau_p,
                       u64* __restrict__ cand,
                       unsigned* __restrict__ gcut)
{
    __shared__ __align__(16) short Bs[CH_BYTES / 2];   // 32 KB fragment buffer
    __shared__ __align__(16) float St[QT * SLD];       // 34.8 KB score tile / end scratch
    __shared__ float scv[2 * QT];                      // published half-stream cutoffs

    const int tid   = threadIdx.x;
    const int lane  = tid & 63;
    const int quad  = lane >> 4;
    const int mrow  = lane & 15;
    const int wv    = tid >> 6;
    const int qbase = blockIdx.y * QT;

    const float nhit = -0.5f * expf(-log_tau_p[0]);

    // ---- build persistent A fragments (hi+lo) in registers ----
    bf16x8 ahi[2][4], alo[2][4];
    #pragma unroll
    for (int mt = 0; mt < 2; ++mt) {
        const float* qrow = query + (size_t)(qbase + wv * 32 + mt * 16 + mrow) * DS;
        #pragma unroll
        for (int ks = 0; ks < 4; ++ks) {
            int kq = ks * 32 + quad * 8;
            int d0 = kq & 63;
            bool lin = kq >= 64;
            bf16x8 h, l;
            #pragma unroll
            for (int j = 0; j < 8; ++j) {
                float v = qrow[d0 + j];
                float x = lin ? (-2.0f * v) : (v * v);
                __bf16 hb = (__bf16)x;
                h[j] = hb;
                l[j] = (__bf16)(x - (float)hb);
            }
            ahi[mt][ks] = h; alo[mt][ks] = l;
        }
    }

    // ---- per-thread top-16 state (query = tid&127, half = tid>>7) ----
    float ts[16]; int ti[16];
    #pragma unroll
    for (int i = 0; i < 16; ++i) { ts[i] = -INFINITY; ti[i] = 0; }
    float mymin = -INFINITY;
    const int qloc = tid & 127;
    const int half = tid >> 7;
    if (tid < 2 * QT) scv[tid] = -INFINITY;
    unsigned* const gslot = gcut + qbase + qloc;

    const char* BsB = (const char*)Bs;

    // ---- stage first chunk ----
    int c = blockIdx.x;
    {
        const char* src = bprep + (size_t)c * CH_BYTES;
        #pragma unroll
        for (int i = 0; i < 8; ++i) {
            int s = tid + i * 256;
            async_cp16(src + s * 16, (void*)(BsB + s * 16));
        }
    }
    __syncthreads();   // drains vmcnt -> Bs ready; scv init visible

    for (int it = 0; it < CHUNKS_PER_BLK; ++it) {
        const int nbase = c * BC;
        const int cn    = c + PCH;
        const bool more = (it + 1) < CHUNKS_PER_BLK;

        // publish own 16th-best AND fetch freshest global cutoff in ONE
        // device-scope RMW (atomic-as-read: immune to stale clean L2 lines).
        // Issued here so its latency hides under the MFMA phase; result is
        // consumed after two barriers (vmcnt fully drained by then).
        unsigned eg = atomicMax(gslot, map_f32(mymin));

        float2 ml[4];
        #pragma unroll
        for (int nt = 0; nt < 4; ++nt)
            ml[nt] = *(const float2*)&m2la[(size_t)(nbase + nt * 16 + mrow) * 2];

        // ---- MFMA: 4 ntiles x 2 mtiles x 4 ksteps x 3 products ----
        f32x4 acc[2][4];
        #pragma unroll
        for (int nt = 0; nt < 4; ++nt) {
            bf16x8 bh[4], bl[4];
            #pragma unroll
            for (int ks = 0; ks < 4; ++ks) {
                bh[ks] = *(const bf16x8*)(BsB + nt * 4096 + ks * 1024 + lane * 16);
                bl[ks] = *(const bf16x8*)(BsB + SPLIT_OFF + nt * 4096 + ks * 1024 + lane * 16);
            }
            #pragma unroll
            for (int mt = 0; mt < 2; ++mt) {
                f32x4 a = {0.0f, 0.0f, 0.0f, 0.0f};
                #pragma unroll
                for (int ks = 0; ks < 4; ++ks) {
                    a = __builtin_amdgcn_mfma_f32_16x16x32_bf16(ahi[mt][ks], bh[ks], a, 0, 0, 0);
                    a = __builtin_amdgcn_mfma_f32_16x16x32_bf16(ahi[mt][ks], bl[ks], a, 0, 0, 0);
                    a = __builtin_amdgcn_mfma_f32_16x16x32_bf16(alo[mt][ks], bh[ks], a, 0, 0, 0);
                }
                acc[mt][nt] = a;
            }
        }
        __syncthreads();   // B1: frag reads done; Bs reusable

        if (more) {
            const char* src = bprep + (size_t)cn * CH_BYTES;
            #pragma unroll
            for (int i = 0; i < 8; ++i) {
                int s = tid + i * 256;
                async_cp16(src + s * 16, (void*)(BsB + s * 16));
            }
        }

        // ---- epilogue: log-score -> Stile ----
        #pragma unroll
        for (int mt = 0; mt < 2; ++mt)
            #pragma unroll
            for (int nt = 0; nt < 4; ++nt) {
                float m2 = ml[nt].x, la = ml[nt].y;
                #pragma unroll
                for (int reg = 0; reg < 4; ++reg) {
                    float sc = nhit * (acc[mt][nt][reg] + m2) + la;
                    St[(wv * 32 + mt * 16 + quad * 4 + reg) * SLD + nt * 16 + mrow] = sc;
                }
            }
        __syncthreads();   // B2: Stile ready

        // ---- scan: branchless screen + lane-local survivor iteration ----
        {
            volatile float* vsc = scv;
            float ocut = vsc[(half ^ 1) * QT + qloc];
            float gc   = unmap_f32(eg);          // global cutoff (monotone lower bound of final 16th)
            float bcut = fmaxf(ocut, gc);
            float cut  = fmaxf(mymin, bcut);
            const float* rowp = &St[qloc * SLD + half * 32];
            unsigned gm = 0u;
            #pragma unroll
            for (int i = 0; i < 8; ++i) {
                float4 v = ((const float4*)rowp)[i];
                float mx = fmaxf(fmaxf(v.x, v.y), fmaxf(v.z, v.w));
                if (mx > cut) gm |= (1u << i);
            }
            while (__any(gm != 0u)) {
                if (gm) {
                    int i = __ffs(gm) - 1;
                    gm &= gm - 1u;
                    float4 v = ((const float4*)rowp)[i];
                    int b0 = nbase + half * 32 + i * 4;
                    if (v.x > cut) { ins16(ts, ti, mymin, v.x, b0);     cut = fmaxf(mymin, bcut); }
                    if (v.y > cut) { ins16(ts, ti, mymin, v.y, b0 + 1); cut = fmaxf(mymin, bcut); }
                    if (v.z > cut) { ins16(ts, ti, mymin, v.z, b0 + 2); cut = fmaxf(mymin, bcut); }
                    if (v.w > cut) { ins16(ts, ti, mymin, v.w, b0 + 3); cut = fmaxf(mymin, bcut); }
                }
            }
            vsc[half * QT + qloc] = mymin;   // publish (monotone; races benign)
        }
        __syncthreads();   // B3: scans done (Stile free); prefetched Bs ready
        c = cn;
    }
    __syncthreads();

    // ---- merge the two half-streams per query, write per-block top-16 ----
    u64* SK = (u64*)St;                 // [128][33] u64 = 33.8 KB (fits in St)
    #pragma unroll
    for (int i = 0; i < 16; ++i)
        SK[qloc * 33 + half * 16 + i] =
            ((u64)map_f32(ts[i]) << 32) | (u64)(0xFFFFFFFFu - (unsigned)ti[i]);
    __syncthreads();

    if (tid < QT) {
        u64* row = SK + tid * 33;
        u64* dst = cand + (size_t)(qbase + tid) * CPQ + blockIdx.x * KSEL;
        for (int r = 0; r < KSEL; ++r) {
            int bm = 0; u64 bv = row[0];
            #pragma unroll 4
            for (int j = 1; j < 32; ++j) { u64 v = row[j]; if (v > bv) { bv = v; bm = j; } }
            row[bm] = 0;
            dst[r] = bv;
        }
    }
}

// ---------------- global merge + exact recompute + compositing ----------------
__global__ __launch_bounds__(256)
void merge_composite_kernel(const float* __restrict__ query,
                            const float* __restrict__ mu,
                            const float* __restrict__ log_var,
                            const float* __restrict__ raw_alpha,
                            const float* __restrict__ features,
                            const float* __restrict__ log_tau_p,
                            const u64* __restrict__ cand,
                            float* __restrict__ out)
{
    const int q   = blockIdx.x;
    const int tid = threadIdx.x;
    const int wv = tid >> 6, lane = tid & 63;

    __shared__ u64   wtop[4 * KSEL];
    __shared__ int   sel[KSEL];
    __shared__ float w_sh[KSEL];
    __shared__ float mah[KSEL];
    __shared__ float alp[KSEL];

    // 1024 keys: each wave owns 256 contiguous (4 per lane)
    u64 k[4];
    #pragma unroll
    for (int r = 0; r < 4; ++r)
        k[r] = cand[(size_t)q * CPQ + wv * 256 + r * 64 + lane];

    // wave-local top-16 (no barriers)
    for (int r = 0; r < KSEL; ++r) {
        u64 m = k[0];
        #pragma unroll
        for (int j = 1; j < 4; ++j) if (k[j] > m) m = k[j];
        #pragma unroll
        for (int off = 32; off > 0; off >>= 1) {
            unsigned hi = __shfl_xor((unsigned)(m >> 32), off);
            unsigned lo = __shfl_xor((unsigned)(m & 0xFFFFFFFFu), off);
            u64 o = ((u64)hi << 32) | lo;
            if (o > m) m = o;
        }
        if (lane == 0) wtop[wv * KSEL + r] = m;
        #pragma unroll
        for (int j = 0; j < 4; ++j) if (k[j] == m) k[j] = 0ull;  // keys unique
    }
    __syncthreads();

    // wave 0: merge 64 -> 16 (shuffle argmax rounds)
    if (wv == 0) {
        u64 kk = wtop[lane];
        for (int r = 0; r < KSEL; ++r) {
            u64 m = kk;
            #pragma unroll
            for (int off = 32; off > 0; off >>= 1) {
                unsigned hi = __shfl_xor((unsigned)(m >> 32), off);
                unsigned lo = __shfl_xor((unsigned)(m & 0xFFFFFFFFu), off);
                u64 o = ((u64)hi << 32) | lo;
                if (o > m) m = o;
            }
            if (kk == m) kk = 0ull;
            if (lane == 0)
                sel[r] = (int)(0xFFFFFFFFu - (unsigned)(m & 0xFFFFFFFFull));
        }
    }
    __syncthreads();

    // exact mahal per selected blob (direct gathered form, like reference)
    for (int r = wv; r < KSEL; r += 4) {
        int bi = sel[r];
        float qd = query[(size_t)q * DS + lane];
        float mv = mu[(size_t)bi * DS + lane];
        float d  = qd - mv;
        float t  = d * d * expf(-log_var[(size_t)bi * DS + lane]);
        #pragma unroll
        for (int off = 32; off > 0; off >>= 1) t += __shfl_down(t, off);
        if (lane == 0) {
            mah[r] = t;
            alp[r] = 1.0f / (1.0f + expf(-raw_alpha[bi]));
        }
    }
    __syncthreads();

    if (tid == 0) {
        float tau = expf(log_tau_p[0]);
        float cap = 0.3f / 16.0f;
        float logT = 0.0f;
        for (int r = 0; r < KSEL; ++r) {
            float K   = expf(-0.5f * mah[r] / tau);
            float eff = fminf(alp[r] * K, cap);
            w_sh[r]   = eff * expf(logT);
            logT     += log1pf(-fminf(eff, 1.0f - 1e-6f));
        }
        out[(size_t)BQ * DF + q] = expf(logT);
    }
    __syncthreads();

    {
        float a = 0.0f;
        #pragma unroll
        for (int r = 0; r < KSEL; ++r)
            a += w_sh[r] * features[(size_t)sel[r] * DF + tid];
        out[(size_t)q * DF + tid] = a;
    }
}

// ---------------- launch ----------------
extern "C" void kernel_launch(void* const* d_in, const int* in_sizes, int n_in,
                              void* d_out, int out_size, void* d_ws, size_t ws_size,
                              hipStream_t stream)
{
    (void)in_sizes; (void)n_in; (void)out_size; (void)ws_size;
    const float* query     = (const float*)d_in[0];
    const float* mu        = (const float*)d_in[1];
    const float* log_var   = (const float*)d_in[2];
    const float* raw_alpha = (const float*)d_in[3];
    const float* features  = (const float*)d_in[4];
    const float* log_tau   = (const float*)d_in[5];
    float* out = (float*)d_out;

    // ws layout: Bprep 64 MB | m2la 1 MB | cand 8 MB
    char*  bprep = (char*)d_ws;
    float* m2la  = (float*)((char*)d_ws + (size_t)NCHUNK * CH_BYTES);
    u64*   cand  = (u64*)((char*)d_ws + (size_t)NCHUNK * CH_BYTES + (size_t)NB * 2 * 4);
    // global per-query cutoffs: borrow the t_residual tail of `out` (4 KB);
    // merge_composite_kernel fully overwrites it afterwards.
    unsigned* gcut = (unsigned*)(out + (size_t)BQ * DF);

    prep_kernel<<<(NB * 8) / 256, 256, 0, stream>>>(mu, log_var, raw_alpha, bprep, m2la, gcut);

    dim3 g2(PCH, BQ / QT);
    score_topk_kernel<<<g2, 256, 0, stream>>>(query, bprep, m2la, log_tau, cand, gcut);

    merge_composite_kernel<<<BQ, 256, 0, stream>>>(query, mu, log_var, raw_alpha,
                                                   features, log_tau, cand, out);
}